// Round 5
// baseline (60.367 us; speedup 1.0000x reference)
//
#include <hip/hip_runtime.h>

// out[b,s,d] = relu(x[b,s] * W[s,d] + bias[s,d])
// B=256, S=512, D=512 (fp32). Write-bandwidth kernel: 268 MB out.
//
// Round history: nt-stores regress (r2: 65us); hoisting W / scalar-x neutral
// (r3/r4: ~50us). All issue-side variants pin at ~5.4 TB/s write while
// fillBuffer streams at 7.0 TB/s. Hypothesis: 8MB inter-store jumps cause
// HBM row-buffer thrash. This round: PER-WAVE CONTIGUOUS streams.
//
// Mapping: wave wid (0..8191) owns float4 range [wid*2048, (wid+1)*2048)
//   iteration k (0..31): i = wid*2048 + k*64 + lane   (32 KB sequential)
//   bs0 = wid*16 (16-aligned, within one b); s0 = bs0 & 511
//   W/bias index collapses to wbase + k*64 + lane -> also sequential 32 KB.
//   x: 16 contiguous wave-uniform floats -> one scalar dwordx16 load.

typedef float __attribute__((ext_vector_type(4))) floatx4;

constexpr int ITERS = 32;   // 32 x 1KB = 32 KB per wave; 8192 waves cover 268 MB

__global__ void __launch_bounds__(256) od2d_kernel(
    const float*   __restrict__ x,    // [B*S]
    const floatx4* __restrict__ W4,   // [S*128]
    const floatx4* __restrict__ b4,   // [S*128]
    floatx4*       __restrict__ o4)   // [B*S*128]
{
    const unsigned lane = threadIdx.x & 63;
    const unsigned wid  = blockIdx.x * 4 + (threadIdx.x >> 6);  // 0..8191
    const unsigned base = wid * 2048;            // float4 index of wave base
    const unsigned bs0  = base >> 7;             // = wid*16, wave-uniform
    const unsigned wbase = (bs0 & 511) << 7;     // W/bias float4 base

    // 16 contiguous x values, wave-uniform -> scalar loads (s_load_dwordx16).
    const float* xp = x + __builtin_amdgcn_readfirstlane(bs0);
    float xs[16];
    #pragma unroll
    for (int j = 0; j < 16; ++j) xs[j] = xp[j];

    unsigned oi = base + lane;       // output float4 index, += 64/iter
    unsigned wi = wbase + lane;      // W/bias float4 index, += 64/iter
    #pragma unroll
    for (int k = 0; k < ITERS; ++k) {
        const float xv = xs[k >> 1];
        const floatx4 w  = W4[wi];
        const floatx4 bb = b4[wi];
        floatx4 r;
        r.x = fmaxf(fmaf(xv, w.x, bb.x), 0.0f);
        r.y = fmaxf(fmaf(xv, w.y, bb.y), 0.0f);
        r.z = fmaxf(fmaf(xv, w.z, bb.z), 0.0f);
        r.w = fmaxf(fmaf(xv, w.w, bb.w), 0.0f);
        o4[oi] = r;
        oi += 64;
        wi += 64;
    }
}

extern "C" void kernel_launch(void* const* d_in, const int* in_sizes, int n_in,
                              void* d_out, int out_size, void* d_ws, size_t ws_size,
                              hipStream_t stream) {
    const float*   x  = (const float*)d_in[0];
    const floatx4* W4 = (const floatx4*)d_in[1];
    const floatx4* b4 = (const floatx4*)d_in[2];
    floatx4* o4 = (floatx4*)d_out;

    od2d_kernel<<<2048, 256, 0, stream>>>(x, W4, b4, o4);
}

// Round 6
// 43.510 us; speedup vs baseline: 1.3874x; 1.3874x over previous
//
#include <hip/hip_runtime.h>

// out[b,s,d] = relu(x[b,s] * W[s,d] + bias[s,d])
// B=256, S=512, D=512 (fp32). Write-bandwidth kernel: 268 MB out.
//
// Round history:
//   r1/r3/r4 (grid-stride, 2048 blocks resident, 8MB window): ~50 us, 5.4 TB/s
//   r2 nontemporal stores: 65 us (regress — keep cached stores)
//   r5 per-wave contiguous 32KB (268MB instantaneous footprint): 60 us (regress)
// Theory: dense sliding write-window wins. Enforce it via BLOCK CHURN:
// 16384 small blocks, each owning a contiguous 16KB chunk; in-order block
// dispatch keeps the active window tight (~2048 resident bids = ~32MB dense,
// sliding front-to-back). Wave stores remain 1KB contiguous per instruction.

typedef float __attribute__((ext_vector_type(4))) floatx4;

__global__ void __launch_bounds__(256) od2d_kernel(
    const float*   __restrict__ x,    // [B*S]
    const floatx4* __restrict__ W4,   // [S*128]
    const floatx4* __restrict__ b4,   // [S*128]
    floatx4*       __restrict__ o4)   // [B*S*128]
{
    const unsigned tid = threadIdx.x;
    const unsigned d4  = tid & 127;
    unsigned i = blockIdx.x * 1024 + tid;   // block chunk: 1024 float4 = 16 KB

    #pragma unroll
    for (int k = 0; k < 4; ++k) {
        const unsigned bs = i >> 7;
        const unsigned wi = ((bs & 511) << 7) + d4;
        const float xv = x[bs];                 // wave-uniform broadcast
        const floatx4 w  = W4[wi];              // L1/L2-resident
        const floatx4 bb = b4[wi];
        floatx4 r;
        r.x = fmaxf(fmaf(xv, w.x, bb.x), 0.0f);
        r.y = fmaxf(fmaf(xv, w.y, bb.y), 0.0f);
        r.z = fmaxf(fmaf(xv, w.z, bb.z), 0.0f);
        r.w = fmaxf(fmaf(xv, w.w, bb.w), 0.0f);
        o4[i] = r;
        i += 256;                               // next 4 KB slice of the chunk
    }
}

extern "C" void kernel_launch(void* const* d_in, const int* in_sizes, int n_in,
                              void* d_out, int out_size, void* d_ws, size_t ws_size,
                              hipStream_t stream) {
    const float*   x  = (const float*)d_in[0];
    const floatx4* W4 = (const floatx4*)d_in[1];
    const floatx4* b4 = (const floatx4*)d_in[2];
    floatx4* o4 = (floatx4*)d_out;

    od2d_kernel<<<16384, 256, 0, stream>>>(x, W4, b4, o4);
}